// Round 12
// baseline (635.425 us; speedup 1.0000x reference)
//
#include <hip/hip_runtime.h>
#include <hip/hip_bf16.h>

#define NB   2048
#define KN   20
#define DF   128
#define DQ   256
#define DKI  384
#define NR1  43008
#define SCALE 0.08838834764831845f

typedef short s16x8 __attribute__((ext_vector_type(8)));
typedef short s16x4 __attribute__((ext_vector_type(4)));
typedef float f32x4 __attribute__((ext_vector_type(4)));

// ---------------- static device scratch ----------------
__device__ __hip_bfloat16 g_S   [(size_t)NR1*256];   // [sf | cte] bf16
__device__ __hip_bfloat16 g_QKH [(size_t)NR1*768];
__device__ __hip_bfloat16 g_CTX [(size_t)NR1*768];   // [ctx_h0 | ctx_h1]
__device__ __hip_bfloat16 g_Ob  [(size_t)NR1*256];
__device__ __hip_bfloat16 g_FC1A[(size_t)NR1*384];   // [oo | sf]
__device__ __hip_bfloat16 g_Hb  [(size_t)NR1*128];
__device__ float          g_out1[(size_t)NR1*DF];
__device__ float          g_Wqk [2*256*768];
__device__ float          g_bqk [2*768];
__device__ unsigned char  g_allm[NR1];
__device__ __hip_bfloat16 g_Bqk[2*196608];  // K=256,N=768 tiled
__device__ __hip_bfloat16 g_Bv [4*49152];   // per (L,h): K=384,N=128 tiled
__device__ __hip_bfloat16 g_Bo [2*65536];   // K=256,N=256
__device__ __hip_bfloat16 g_B1 [2*49152];   // K=384,N=128
__device__ __hip_bfloat16 g_B2 [2*16384];   // K=128,N=128

__device__ __forceinline__ short f2bf(float v) {
  union { __hip_bfloat16 h; short s; } u; u.h = __float2bfloat16(v); return u.s;
}
__device__ __forceinline__ float2 bfpair(unsigned u) {
  union { unsigned u2; float f; } a, b;
  a.u2 = u << 16;          // low bf16
  b.u2 = u & 0xFFFF0000u;  // high bf16
  float2 r; r.x = a.f; r.y = b.f; return r;
}
__device__ __forceinline__ s16x4 pack4(float x, float y, float z, float w) {
  s16x4 o; o[0]=f2bf(x); o[1]=f2bf(y); o[2]=f2bf(z); o[3]=f2bf(w); return o;
}
__device__ __forceinline__ unsigned packbf2(float2 v) {
  return (unsigned)(unsigned short)f2bf(v.x) | ((unsigned)(unsigned short)f2bf(v.y) << 16);
}

// ---------------- Wqk = Wq_h @ Wk_h^T fold (per L,h) ----------------
__global__ __launch_bounds__(256)
void k_wqk(const float* __restrict__ Wq, const float* __restrict__ Wk,
           const float* __restrict__ bq) {
  int idx = blockIdx.x*256 + threadIdx.x;          // 2*256*768 = 393216
  int L = idx / 196608, rem = idx % 196608;
  int n = rem >> 8, co = rem & 255;
  int h = n / 384, i = n - h*384;
  const float* wqp = Wq + (size_t)L*DQ*DQ  + (size_t)co*DQ + h*128;
  const float* wkp = Wk + (size_t)L*DKI*DQ + (size_t)i*DQ  + h*128;
  float acc = 0.f;
  #pragma unroll 4
  for (int c = 0; c < 128; ++c) acc += wqp[c]*wkp[c];
  g_Wqk[(size_t)(L*256 + co)*768 + n] = acc;
  if (co == 0) {
    const float* bqp = bq + L*DQ + h*128;
    float b = 0.f;
    for (int c = 0; c < 128; ++c) b += bqp[c]*wkp[c];
    g_bqk[L*768 + n] = b;
  }
}

// ---------------- generic B-tiler: f32 [K][ldsrc] -> tiled bf16 ----------------
__global__ __launch_bounds__(256)
void k_btile(const float* __restrict__ src, int ldsrc, int K, int N,
             __hip_bfloat16* __restrict__ dst) {
  int slot = blockIdx.x*256 + threadIdx.x;
  if (slot >= (K*N)/8) return;
  int cl = slot & 15, t = slot >> 4;
  int kgn = K >> 3;
  int kg = t % kgn, nt = t / kgn;
  int n = nt*16 + cl;
  s16x8 o;
  #pragma unroll
  for (int e = 0; e < 8; ++e) o[e] = f2bf(src[(size_t)(kg*8 + e)*ldsrc + n]);
  *(s16x8*)(dst + (size_t)slot*8) = o;
}

// ---------------- prep: S = [sf|cte] bf16, FC1A[:,256:384] = sf ----------------
template<int L>
__global__ __launch_bounds__(256)
void k_prep(const float* __restrict__ nf, const float* __restrict__ mem,
            const float* __restrict__ tb,
            const int* __restrict__ srcn, const int* __restrict__ nbs) {
  const int tid = threadIdx.x;
  const int rl = tid >> 5, q = tid & 31, d0 = q*4;
  const int r = blockIdx.x*8 + rl;
  float ax, ay, az, aw;
  if (L == 0) {
    int node = (r < NB) ? srcn[r] : nbs[r - NB];
    float4 x = *(const float4*)(mem + (size_t)node*DF + d0);
    float4 y = *(const float4*)(nf  + (size_t)node*DF + d0);
    ax=x.x+y.x; ay=x.y+y.y; az=x.z+y.z; aw=x.w+y.w;
  } else {
    float4 x = *(const float4*)(g_out1 + (size_t)r*DF + d0);
    ax=x.x; ay=x.y; az=x.z; aw=x.w;
  }
  *(s16x4*)(g_S + (size_t)r*256 + d0) = pack4(ax, ay, az, aw);
  *(s16x4*)(g_S + (size_t)r*256 + 128 + d0) =
      pack4(cosf(tb[d0]), cosf(tb[d0+1]), cosf(tb[d0+2]), cosf(tb[d0+3]));
  *(s16x4*)(g_FC1A + (size_t)r*384 + 256 + d0) = pack4(ax, ay, az, aw);
}

// ---------------- edge kernel v6: wave-per-row + online softmax +
//                  explicit double-buffered chunk prefetch (software pipeline) ----
// lane owns dims {2*lane, 2*lane+1}; lane e (<20) holds edge-e metadata.
template<int L>
__global__ __launch_bounds__(256, 4)
void k_edge(const float* __restrict__ nf, const float* __restrict__ ef,
            const float* __restrict__ mem, const float* __restrict__ tsv,
            const float* __restrict__ ets, const float* __restrict__ etn,
            const float* __restrict__ tw,  const float* __restrict__ tb,
            const int* __restrict__ nbs, const int* __restrict__ eis,
            const int* __restrict__ nbn, const int* __restrict__ ein,
            const __hip_bfloat16* __restrict__ QKH,
            __hip_bfloat16* __restrict__ CTX)
{
  const int tid = threadIdx.x;
  const int lane = tid & 63, w = tid >> 6;
  const int r = blockIdx.x*4 + w;

  // ---- metadata in lane registers (lane e holds edge e) ----
  int raw_ = 1, nd_ = 0, ei_ = 0; float dt_ = 0.f;
  if (lane < KN) {
    if (L == 0) {
      if (r < NB) { raw_ = nbs[r*KN+lane]; nd_ = raw_; ei_ = eis[r*KN+lane]; dt_ = tsv[r] - ets[r*KN+lane]; }
      else { int mm = (r-NB)*KN + lane; raw_ = nbn[mm]; nd_ = raw_; ei_ = ein[mm]; dt_ = tsv[(r-NB)/KN] - etn[mm]; }
    } else {
      raw_ = nbs[r*KN+lane]; nd_ = NB + r*KN + lane; ei_ = eis[r*KN+lane]; dt_ = tsv[r] - ets[r*KN+lane];
    }
  }
  unsigned long long bal = __ballot(lane < KN && raw_ == 0);
  unsigned mb = (unsigned)(bal & 0xFFFFFull);
  if (lane == 0) g_allm[r] = (mb == 0xFFFFFu) ? 1 : 0;

  // ---- per-lane constants: q slices + time-table slice ----
  const __hip_bfloat16* Qr = QKH + (size_t)r*768;
  float2 q0[3], q1[3];
  #pragma unroll
  for (int seg = 0; seg < 3; ++seg) {
    q0[seg] = bfpair(*(const unsigned*)(Qr +       seg*128 + 2*lane));
    q1[seg] = bfpair(*(const unsigned*)(Qr + 384 + seg*128 + 2*lane));
  }
  float2 twr = *(const float2*)(tw + 2*lane);
  float2 tbr = *(const float2*)(tb + 2*lane);

  // ---- online-softmax state ----
  float m0 = -3.0e38f, m1 = -3.0e38f;
  float su0 = 0.f, su1 = 0.f;
  float2 c0n = {0,0}, c0t = {0,0}, c0e = {0,0};
  float2 c1n = {0,0}, c1t = {0,0}, c1e = {0,0};

  // ---- double-buffered 5-edge chunks: loads of next chunk issued BEFORE
  //      computing current chunk (keeps >=15 loads in flight under compute) ----
  float2 Avm[5], Avf[5], Avef[5]; float Adtr[5];
  float2 Bvm[5], Bvf[5], Bvef[5]; float Bdtr[5];

  #define LOADCH(P, C0) {                                                    \
    _Pragma("unroll")                                                        \
    for (int e = 0; e < 5; ++e) {                                            \
      int ndv = __shfl(nd_, (C0) + e);                                       \
      int eiv = __shfl(ei_, (C0) + e);                                       \
      P##dtr[e] = __shfl(dt_, (C0) + e);                                     \
      if (L == 0) {                                                          \
        P##vm[e] = *(const float2*)(mem + (size_t)ndv*DF + 2*lane);          \
        P##vf[e] = *(const float2*)(nf  + (size_t)ndv*DF + 2*lane);          \
      } else {                                                               \
        P##vm[e] = *(const float2*)(g_out1 + (size_t)ndv*DF + 2*lane);       \
      }                                                                      \
      P##vef[e] = *(const float2*)(ef + (size_t)eiv*DF + 2*lane);            \
    } }

  #define COMPCH(P, C0) {                                                    \
    _Pragma("unroll")                                                        \
    for (int e = 0; e < 5; ++e) {                                            \
      float2 vn;                                                             \
      if (L == 0) { vn.x = P##vm[e].x + P##vf[e].x; vn.y = P##vm[e].y + P##vf[e].y; } \
      else        vn = P##vm[e];                                             \
      float2 vt;                                                             \
      vt.x = __cosf(P##dtr[e]*twr.x + tbr.x);                                \
      vt.y = __cosf(P##dtr[e]*twr.y + tbr.y);                                \
      float p0 = vn.x*q0[0].x + vn.y*q0[0].y + vt.x*q0[1].x + vt.y*q0[1].y   \
               + P##vef[e].x*q0[2].x + P##vef[e].y*q0[2].y;                  \
      float p1 = vn.x*q1[0].x + vn.y*q1[0].y + vt.x*q1[1].x + vt.y*q1[1].y   \
               + P##vef[e].x*q1[2].x + P##vef[e].y*q1[2].y;                  \
      _Pragma("unroll")                                                      \
      for (int off = 1; off < 64; off <<= 1) {                               \
        p0 += __shfl_xor(p0, off);                                           \
        p1 += __shfl_xor(p1, off);                                           \
      }                                                                      \
      const bool msk = (mb >> ((C0) + e)) & 1u;                              \
      float s0 = msk ? -1e9f : p0*SCALE;                                     \
      float s1 = msk ? -1e9f : p1*SCALE;                                     \
      if (s0 > m0) {                                                         \
        float f = __expf(m0 - s0);                                           \
        su0 *= f;                                                            \
        c0n.x *= f; c0n.y *= f; c0t.x *= f; c0t.y *= f; c0e.x *= f; c0e.y *= f; \
        m0 = s0;                                                             \
      }                                                                      \
      float w0 = __expf(s0 - m0);                                            \
      su0 += w0;                                                             \
      c0n.x += w0*vn.x;    c0n.y += w0*vn.y;                                 \
      c0t.x += w0*vt.x;    c0t.y += w0*vt.y;                                 \
      c0e.x += w0*P##vef[e].x; c0e.y += w0*P##vef[e].y;                      \
      if (s1 > m1) {                                                         \
        float f = __expf(m1 - s1);                                           \
        su1 *= f;                                                            \
        c1n.x *= f; c1n.y *= f; c1t.x *= f; c1t.y *= f; c1e.x *= f; c1e.y *= f; \
        m1 = s1;                                                             \
      }                                                                      \
      float w1 = __expf(s1 - m1);                                            \
      su1 += w1;                                                             \
      c1n.x += w1*vn.x;    c1n.y += w1*vn.y;                                 \
      c1t.x += w1*vt.x;    c1t.y += w1*vt.y;                                 \
      c1e.x += w1*P##vef[e].x; c1e.y += w1*P##vef[e].y;                      \
    } }

  LOADCH(A, 0)
  LOADCH(B, 5)
  COMPCH(A, 0)
  LOADCH(A, 10)
  COMPCH(B, 5)
  LOADCH(B, 15)
  COMPCH(A, 10)
  COMPCH(B, 15)

  #undef LOADCH
  #undef COMPCH

  // ---- normalize + coalesced bf16 CTX write ----
  float i0 = 1.f / su0, i1 = 1.f / su1;
  c0n.x *= i0; c0n.y *= i0; c0t.x *= i0; c0t.y *= i0; c0e.x *= i0; c0e.y *= i0;
  c1n.x *= i1; c1n.y *= i1; c1t.x *= i1; c1t.y *= i1; c1e.x *= i1; c1e.y *= i1;
  unsigned* C32 = (unsigned*)(CTX + (size_t)r*768);
  C32[0*64 + lane] = packbf2(c0n);
  C32[1*64 + lane] = packbf2(c0t);
  C32[2*64 + lane] = packbf2(c0e);
  C32[3*64 + lane] = packbf2(c1n);
  C32[4*64 + lane] = packbf2(c1t);
  C32[5*64 + lane] = packbf2(c1e);
}

// ---------------- generic MFMA GEMM: C[M,N] = A(row-major bf16) @ B(tiled) ----------------
template<int KT, bool F32OUT, bool RELU, bool MASK>
__global__ __launch_bounds__(256, 2)
void k_gemm(const __hip_bfloat16* __restrict__ A, int lda,
            const __hip_bfloat16* __restrict__ B, int kgtot, int nblk,
            void* __restrict__ Cout, int ldc,
            const float* __restrict__ bias,
            const unsigned char* __restrict__ mask)
{
  __shared__ __hip_bfloat16 As[2][128*40];
  __shared__ __hip_bfloat16 Bs[2][128*32];
  const int tid  = threadIdx.x;
  const int lane = tid & 63, wid = tid >> 6;
  const int wm = wid >> 1, wn = wid & 1;
  const int rl = lane & 15, kgs = lane >> 4;
  const int bm = blockIdx.x / nblk, bn = blockIdx.x % nblk;

  f32x4 acc[4][4];
  #pragma unroll
  for (int i = 0; i < 4; ++i)
    #pragma unroll
    for (int j = 0; j < 4; ++j) acc[i][j] = (f32x4){0.f,0.f,0.f,0.f};

  #define STAGE(T, BUF) {                                                      \
    _Pragma("unroll")                                                          \
    for (int i_ = 0; i_ < 2; ++i_) {                                           \
      int row_ = i_*64 + (tid >> 2), kc_ = (tid & 3)*8;                        \
      s16x8 v_ = *(const s16x8*)(A + (size_t)(bm*128 + row_)*lda + (T)*32 + kc_); \
      *(s16x8*)(&As[BUF][row_*40 + kc_]) = v_;                                 \
    }                                                                          \
    _Pragma("unroll")                                                          \
    for (int i_ = 0; i_ < 2; ++i_) {                                           \
      int slot_ = i_*256 + tid;                                                \
      int nt_ = slot_ >> 6, kg_ = (slot_ >> 4) & 3, cl_ = slot_ & 15;          \
      s16x8 w_ = *(const s16x8*)(B + ((size_t)(bn*8 + nt_)*kgtot + (T)*4 + kg_)*128 + cl_*8); \
      *(s16x8*)(&Bs[BUF][slot_*8]) = w_;                                       \
    } }

  STAGE(0, 0);
  __syncthreads();
  int buf = 0;
  for (int t = 0; t < KT; ++t) {
    if (t < KT-1) STAGE(t+1, buf ^ 1);
    s16x8 af[4], bfm[4];
    #pragma unroll
    for (int mtl = 0; mtl < 4; ++mtl)
      af[mtl] = *(const s16x8*)(&As[buf][(wm*64 + mtl*16 + rl)*40 + kgs*8]);
    #pragma unroll
    for (int ntl = 0; ntl < 4; ++ntl)
      bfm[ntl] = *(const s16x8*)(&Bs[buf][((wn*4 + ntl)*4 + kgs)*128 + rl*8]);
    #pragma unroll
    for (int mtl = 0; mtl < 4; ++mtl)
      #pragma unroll
      for (int ntl = 0; ntl < 4; ++ntl)
        acc[mtl][ntl] = __builtin_amdgcn_mfma_f32_16x16x32_bf16(af[mtl], bfm[ntl], acc[mtl][ntl], 0, 0, 0);
    __syncthreads();
    buf ^= 1;
  }
  #undef STAGE

  #pragma unroll
  for (int mtl = 0; mtl < 4; ++mtl) {
    #pragma unroll
    for (int ntl = 0; ntl < 4; ++ntl) {
      int gcol = bn*128 + wn*64 + ntl*16 + rl;
      float bb = bias ? bias[gcol] : 0.f;
      #pragma unroll
      for (int rg = 0; rg < 4; ++rg) {
        int grow = bm*128 + wm*64 + mtl*16 + kgs*4 + rg;
        float v = acc[mtl][ntl][rg] + bb;
        if (RELU) v = fmaxf(v, 0.f);
        if (MASK) { if (mask[grow]) v = 0.f; }
        if (F32OUT) ((float*)Cout)[(size_t)grow*ldc + gcol] = v;
        else ((__hip_bfloat16*)Cout)[(size_t)grow*ldc + gcol] = __float2bfloat16(v);
      }
    }
  }
}

// ---------------- host ----------------
extern "C" void kernel_launch(void* const* d_in, const int* in_sizes, int n_in,
                              void* d_out, int out_size, void* d_ws, size_t ws_size,
                              hipStream_t stream) {
  (void)in_sizes; (void)n_in; (void)out_size; (void)ws_size; (void)d_ws;
  const float* nf   = (const float*)d_in[0];
  const float* ef   = (const float*)d_in[1];
  const float* mem  = (const float*)d_in[2];
  const float* tsv  = (const float*)d_in[3];
  const float* ets  = (const float*)d_in[4];
  const float* etn  = (const float*)d_in[5];
  const float* tw   = (const float*)d_in[6];
  const float* tb   = (const float*)d_in[7];
  const float* Wq   = (const float*)d_in[8];
  const float* bq   = (const float*)d_in[9];
  const float* Wk   = (const float*)d_in[10];
  const float* bv   = (const float*)d_in[13];
  const float* Wv   = (const float*)d_in[12];
  const float* Wo   = (const float*)d_in[14];
  const float* bo   = (const float*)d_in[15];
  const float* f1w  = (const float*)d_in[16];
  const float* f1b  = (const float*)d_in[17];
  const float* f2w  = (const float*)d_in[18];
  const float* f2b  = (const float*)d_in[19];
  const int* srcn   = (const int*)d_in[20];
  const int* nbs    = (const int*)d_in[21];
  const int* eis    = (const int*)d_in[22];
  const int* nbn    = (const int*)d_in[23];
  const int* ein    = (const int*)d_in[24];
  float* out = (float*)d_out;

  __hip_bfloat16 *S, *QKH, *CTX, *Ob, *FC1A, *Hb, *Bqk, *Bv, *Bo, *B1, *B2;
  float *Wqkf, *bqkf, *out1f;
  unsigned char* allm;
  hipGetSymbolAddress((void**)&S,    HIP_SYMBOL(g_S));
  hipGetSymbolAddress((void**)&QKH,  HIP_SYMBOL(g_QKH));
  hipGetSymbolAddress((void**)&CTX,  HIP_SYMBOL(g_CTX));
  hipGetSymbolAddress((void**)&Ob,   HIP_SYMBOL(g_Ob));
  hipGetSymbolAddress((void**)&FC1A, HIP_SYMBOL(g_FC1A));
  hipGetSymbolAddress((void**)&Hb,   HIP_SYMBOL(g_Hb));
  hipGetSymbolAddress((void**)&Bqk,  HIP_SYMBOL(g_Bqk));
  hipGetSymbolAddress((void**)&Bv,   HIP_SYMBOL(g_Bv));
  hipGetSymbolAddress((void**)&Bo,   HIP_SYMBOL(g_Bo));
  hipGetSymbolAddress((void**)&B1,   HIP_SYMBOL(g_B1));
  hipGetSymbolAddress((void**)&B2,   HIP_SYMBOL(g_B2));
  hipGetSymbolAddress((void**)&Wqkf, HIP_SYMBOL(g_Wqk));
  hipGetSymbolAddress((void**)&bqkf, HIP_SYMBOL(g_bqk));
  hipGetSymbolAddress((void**)&out1f,HIP_SYMBOL(g_out1));
  hipGetSymbolAddress((void**)&allm, HIP_SYMBOL(g_allm));

  // weight prep
  hipLaunchKernelGGL(k_wqk, dim3(1536), dim3(256), 0, stream, Wq, Wk, bq);
  for (int L = 0; L < 2; ++L) {
    hipLaunchKernelGGL(k_btile, dim3(96), dim3(256), 0, stream, Wqkf + (size_t)L*256*768, 768, 256, 768, Bqk + (size_t)L*196608);
    for (int h = 0; h < 2; ++h)
      hipLaunchKernelGGL(k_btile, dim3(24), dim3(256), 0, stream, Wv + (size_t)L*DKI*DQ + h*128, 256, 384, 128, Bv + (size_t)(L*2+h)*49152);
    hipLaunchKernelGGL(k_btile, dim3(32), dim3(256), 0, stream, Wo + (size_t)L*DQ*DQ,    256, 256, 256, Bo + (size_t)L*65536);
    hipLaunchKernelGGL(k_btile, dim3(24), dim3(256), 0, stream, f1w + (size_t)L*384*128, 128, 384, 128, B1 + (size_t)L*49152);
    hipLaunchKernelGGL(k_btile, dim3(8),  dim3(256), 0, stream, f2w + (size_t)L*128*128, 128, 128, 128, B2 + (size_t)L*16384);
  }

  // ---- layer 0 (R = 43008) ----
  {
    const int R = NR1, BMg = R/128;
    hipLaunchKernelGGL((k_prep<0>), dim3(R/8), dim3(256), 0, stream, nf, mem, tb, srcn, nbs);
    hipLaunchKernelGGL((k_gemm<8,false,false,false>), dim3(BMg*6), dim3(256), 0, stream,
        S, 256, Bqk, 32, 6, QKH, 768, bqkf, (const unsigned char*)nullptr);
    hipLaunchKernelGGL((k_edge<0>), dim3(R/4), dim3(256), 0, stream,
        nf, ef, mem, tsv, ets, etn, tw, tb, nbs, eis, nbn, ein, QKH, CTX);
    for (int h = 0; h < 2; ++h)
      hipLaunchKernelGGL((k_gemm<12,false,false,false>), dim3(BMg), dim3(256), 0, stream,
          CTX + h*384, 768, Bv + (size_t)h*49152, 48, 1, Ob + h*128, 256, bv + h*128, (const unsigned char*)nullptr);
    hipLaunchKernelGGL((k_gemm<8,false,false,true>), dim3(BMg*2), dim3(256), 0, stream,
        Ob, 256, Bo, 32, 2, FC1A, 384, bo, allm);
    hipLaunchKernelGGL((k_gemm<12,false,true,false>), dim3(BMg), dim3(256), 0, stream,
        FC1A, 384, B1, 48, 1, Hb, 128, f1b, (const unsigned char*)nullptr);
    hipLaunchKernelGGL((k_gemm<4,true,false,false>), dim3(BMg), dim3(256), 0, stream,
        Hb, 128, B2, 16, 1, out1f, 128, f2b, (const unsigned char*)nullptr);
  }
  // ---- layer 1 (R = 2048) ----
  {
    const int R = NB, BMg = R/128;
    hipLaunchKernelGGL((k_prep<1>), dim3(R/8), dim3(256), 0, stream, nf, mem, tb, srcn, nbs);
    hipLaunchKernelGGL((k_gemm<8,false,false,false>), dim3(BMg*6), dim3(256), 0, stream,
        S, 256, Bqk + 196608, 32, 6, QKH, 768, bqkf + 768, (const unsigned char*)nullptr);
    hipLaunchKernelGGL((k_edge<1>), dim3(R/4), dim3(256), 0, stream,
        nf, ef, mem, tsv, ets, etn, tw, tb, nbs, eis, nbn, ein, QKH, CTX);
    for (int h = 0; h < 2; ++h)
      hipLaunchKernelGGL((k_gemm<12,false,false,false>), dim3(BMg), dim3(256), 0, stream,
          CTX + h*384, 768, Bv + (size_t)(2+h)*49152, 48, 1, Ob + h*128, 256, bv + 256 + h*128, (const unsigned char*)nullptr);
    hipLaunchKernelGGL((k_gemm<8,false,false,true>), dim3(BMg*2), dim3(256), 0, stream,
        Ob, 256, Bo + 65536, 32, 2, FC1A, 384, bo + 256, allm);
    hipLaunchKernelGGL((k_gemm<12,false,true,false>), dim3(BMg), dim3(256), 0, stream,
        FC1A, 384, B1 + 49152, 48, 1, Hb, 128, f1b + 128, (const unsigned char*)nullptr);
    hipLaunchKernelGGL((k_gemm<4,true,false,false>), dim3(BMg), dim3(256), 0, stream,
        Hb, 128, B2 + 16384, 16, 1, out, 128, f2b + 128, (const unsigned char*)nullptr);
  }
}

// Round 13
// 556.251 us; speedup vs baseline: 1.1423x; 1.1423x over previous
//
#include <hip/hip_runtime.h>
#include <hip/hip_bf16.h>

#define NB   2048
#define KN   20
#define DF   128
#define DQ   256
#define DKI  384
#define NR1  43008
#define SCALE 0.08838834764831845f

typedef short s16x8 __attribute__((ext_vector_type(8)));
typedef short s16x4 __attribute__((ext_vector_type(4)));
typedef float f32x4 __attribute__((ext_vector_type(4)));

// ---------------- static device scratch ----------------
__device__ __hip_bfloat16 g_S   [(size_t)NR1*128];   // sf only (cte folded into bias)
__device__ __hip_bfloat16 g_QKH [(size_t)NR1*768];
__device__ __hip_bfloat16 g_CTX [(size_t)NR1*768];   // [ctx_h0 | ctx_h1]
__device__ __hip_bfloat16 g_Ob  [(size_t)NR1*256];
__device__ __hip_bfloat16 g_FC1A[(size_t)NR1*384];   // [oo | sf]
__device__ float          g_out1[(size_t)NR1*DF];
__device__ float          g_Wqk [2*256*768];
__device__ float          g_bqk [2*768];
__device__ float          g_bqkv[2*768];             // final qkh bias (cte-folded, scaled)
__device__ unsigned char  g_allm[NR1];
__device__ __hip_bfloat16 g_Bqk[2*98304];   // K=128,N=768 tiled, SCALE-folded
__device__ __hip_bfloat16 g_Bv [4*49152];   // per (L,h): K=384,N=128 tiled
__device__ __hip_bfloat16 g_Bo [2*65536];   // K=256,N=256
__device__ __hip_bfloat16 g_B1 [2*49152];   // K=384,N=128
__device__ __hip_bfloat16 g_B2 [2*16384];   // K=128,N=128

__device__ __forceinline__ short f2bf(float v) {
  union { __hip_bfloat16 h; short s; } u; u.h = __float2bfloat16(v); return u.s;
}
__device__ __forceinline__ float2 bfpair(unsigned u) {
  union { unsigned u2; float f; } a, b;
  a.u2 = u << 16;
  b.u2 = u & 0xFFFF0000u;
  float2 r; r.x = a.f; r.y = b.f; return r;
}
__device__ __forceinline__ s16x4 pack4(float x, float y, float z, float w) {
  s16x4 o; o[0]=f2bf(x); o[1]=f2bf(y); o[2]=f2bf(z); o[3]=f2bf(w); return o;
}
__device__ __forceinline__ unsigned packbf2(float2 v) {
  return (unsigned)(unsigned short)f2bf(v.x) | ((unsigned)(unsigned short)f2bf(v.y) << 16);
}

// ---------------- weight prep 1: Wqk fold + tile Bv/Bo/B1/B2 (one launch) ----------------
__global__ __launch_bounds__(256)
void k_wprep1(const float* __restrict__ Wq, const float* __restrict__ Wk,
              const float* __restrict__ bq, const float* __restrict__ Wv,
              const float* __restrict__ Wo, const float* __restrict__ f1w,
              const float* __restrict__ f2w) {
  int b = blockIdx.x;
  if (b < 1536) {                       // Wqk fold: 2*256*768 outputs
    int idx = b*256 + threadIdx.x;
    int L = idx / 196608, rem = idx % 196608;
    int n = rem >> 8, co = rem & 255;
    int h = n / 384, i = n - h*384;
    const float* wqp = Wq + (size_t)L*DQ*DQ  + (size_t)co*DQ + h*128;
    const float* wkp = Wk + (size_t)L*DKI*DQ + (size_t)i*DQ  + h*128;
    float acc = 0.f;
    #pragma unroll 4
    for (int c = 0; c < 128; ++c) acc += wqp[c]*wkp[c];
    g_Wqk[(size_t)(L*256 + co)*768 + n] = acc;
    if (co == 0) {
      const float* bqp = bq + L*DQ + h*128;
      float bb = 0.f;
      for (int c = 0; c < 128; ++c) bb += bqp[c]*wkp[c];
      g_bqk[L*768 + n] = bb;
    }
    return;
  }
  b -= 1536;
  const float* src; int ldsrc, K, N; __hip_bfloat16* dst;
  if (b < 96)       { int j = b/24; int L=j>>1, h=j&1;
                      src = Wv + (size_t)L*DKI*DQ + h*128; ldsrc=256; K=384; N=128;
                      dst = g_Bv + (size_t)j*49152; b %= 24; }
  else if (b < 160) { b -= 96; int L = b/32;
                      src = Wo + (size_t)L*DQ*DQ; ldsrc=256; K=256; N=256;
                      dst = g_Bo + (size_t)L*65536; b %= 32; }
  else if (b < 208) { b -= 160; int L = b/24;
                      src = f1w + (size_t)L*384*128; ldsrc=128; K=384; N=128;
                      dst = g_B1 + (size_t)L*49152; b %= 24; }
  else              { b -= 208; int L = b/8;
                      src = f2w + (size_t)L*128*128; ldsrc=128; K=128; N=128;
                      dst = g_B2 + (size_t)L*16384; b %= 8; }
  int slot = b*256 + threadIdx.x;
  if (slot >= (K*N)/8) return;
  int cl = slot & 15, t = slot >> 4;
  int kgn = K >> 3;
  int kg = t % kgn, nt = t / kgn;
  int n = nt*16 + cl;
  s16x8 o;
  #pragma unroll
  for (int e = 0; e < 8; ++e) o[e] = f2bf(src[(size_t)(kg*8 + e)*ldsrc + n]);
  *(s16x8*)(dst + (size_t)slot*8) = o;
}

// ---------------- weight prep 2: tile Bqk (K=128, SCALE-folded) + cte-folded bias ----------------
__global__ __launch_bounds__(256)
void k_wprep2(const float* __restrict__ tb) {
  int b = blockIdx.x;
  if (b < 96) {                         // Bqk tiling: 2 L x 48 blocks
    int L = b / 48;
    int slot = (b % 48)*256 + threadIdx.x;   // 12288 slots per L
    int cl = slot & 15, t = slot >> 4;
    int kg = t & 15, nt = t >> 4;
    int n = nt*16 + cl;
    s16x8 o;
    #pragma unroll
    for (int e = 0; e < 8; ++e)
      o[e] = f2bf(g_Wqk[(size_t)(L*256 + kg*8 + e)*768 + n] * SCALE);
    *(s16x8*)(g_Bqk + (size_t)L*98304 + (size_t)slot*8) = o;
  } else {                              // bias: 2*768 entries
    int idx = (b - 96)*256 + threadIdx.x;
    int L = idx / 768, n = idx % 768;
    float acc = g_bqk[idx];
    for (int c = 0; c < 128; ++c)
      acc += cosf(tb[c]) * g_Wqk[(size_t)(L*256 + 128 + c)*768 + n];
    g_bqkv[idx] = acc * SCALE;
  }
}

// ---------------- prep: S = sf bf16 (128), FC1A[:,256:384] = sf ----------------
template<int L>
__global__ __launch_bounds__(256)
void k_prep(const float* __restrict__ nf, const float* __restrict__ mem,
            const int* __restrict__ srcn, const int* __restrict__ nbs) {
  const int tid = threadIdx.x;
  const int rl = tid >> 5, q = tid & 31, d0 = q*4;
  const int r = blockIdx.x*8 + rl;
  float ax, ay, az, aw;
  if (L == 0) {
    int node = (r < NB) ? srcn[r] : nbs[r - NB];
    float4 x = *(const float4*)(mem + (size_t)node*DF + d0);
    float4 y = *(const float4*)(nf  + (size_t)node*DF + d0);
    ax=x.x+y.x; ay=x.y+y.y; az=x.z+y.z; aw=x.w+y.w;
  } else {
    float4 x = *(const float4*)(g_out1 + (size_t)r*DF + d0);
    ax=x.x; ay=x.y; az=x.z; aw=x.w;
  }
  s16x4 p = pack4(ax, ay, az, aw);
  *(s16x4*)(g_S + (size_t)r*128 + d0) = p;
  *(s16x4*)(g_FC1A + (size_t)r*384 + 256 + d0) = p;
}

// ---------------- edge kernel v5 (proven): wave-per-row + online softmax ----------------
template<int L>
__global__ __launch_bounds__(256, 4)
void k_edge(const float* __restrict__ nf, const float* __restrict__ ef,
            const float* __restrict__ mem, const float* __restrict__ tsv,
            const float* __restrict__ ets, const float* __restrict__ etn,
            const float* __restrict__ tw,  const float* __restrict__ tb,
            const int* __restrict__ nbs, const int* __restrict__ eis,
            const int* __restrict__ nbn, const int* __restrict__ ein,
            const __hip_bfloat16* __restrict__ QKH,
            __hip_bfloat16* __restrict__ CTX)
{
  const int tid = threadIdx.x;
  const int lane = tid & 63, w = tid >> 6;
  const int r = blockIdx.x*4 + w;

  int raw_ = 1, nd_ = 0, ei_ = 0; float dt_ = 0.f;
  if (lane < KN) {
    if (L == 0) {
      if (r < NB) { raw_ = nbs[r*KN+lane]; nd_ = raw_; ei_ = eis[r*KN+lane]; dt_ = tsv[r] - ets[r*KN+lane]; }
      else { int mm = (r-NB)*KN + lane; raw_ = nbn[mm]; nd_ = raw_; ei_ = ein[mm]; dt_ = tsv[(r-NB)/KN] - etn[mm]; }
    } else {
      raw_ = nbs[r*KN+lane]; nd_ = NB + r*KN + lane; ei_ = eis[r*KN+lane]; dt_ = tsv[r] - ets[r*KN+lane];
    }
  }
  unsigned long long bal = __ballot(lane < KN && raw_ == 0);
  unsigned mb = (unsigned)(bal & 0xFFFFFull);
  if (lane == 0) g_allm[r] = (mb == 0xFFFFFu) ? 1 : 0;

  const __hip_bfloat16* Qr = QKH + (size_t)r*768;
  float2 q0[3], q1[3];
  #pragma unroll
  for (int seg = 0; seg < 3; ++seg) {
    q0[seg] = bfpair(*(const unsigned*)(Qr +       seg*128 + 2*lane));
    q1[seg] = bfpair(*(const unsigned*)(Qr + 384 + seg*128 + 2*lane));
  }
  float2 twr = *(const float2*)(tw + 2*lane);
  float2 tbr = *(const float2*)(tb + 2*lane);

  float m0 = -3.0e38f, m1 = -3.0e38f;
  float su0 = 0.f, su1 = 0.f;
  float2 c0n = {0,0}, c0t = {0,0}, c0e = {0,0};
  float2 c1n = {0,0}, c1t = {0,0}, c1e = {0,0};

  #pragma unroll
  for (int c0i = 0; c0i < KN; c0i += 5) {
    int nds[5], eir[5]; float dtr[5];
    #pragma unroll
    for (int e = 0; e < 5; ++e) {
      nds[e] = __shfl(nd_, c0i + e);
      eir[e] = __shfl(ei_, c0i + e);
      dtr[e] = __shfl(dt_, c0i + e);
    }
    float2 vm[5], vf[5], vef[5];
    #pragma unroll
    for (int e = 0; e < 5; ++e) {
      if (L == 0) {
        vm[e] = *(const float2*)(mem + (size_t)nds[e]*DF + 2*lane);
        vf[e] = *(const float2*)(nf  + (size_t)nds[e]*DF + 2*lane);
      } else {
        vm[e] = *(const float2*)(g_out1 + (size_t)nds[e]*DF + 2*lane);
      }
      vef[e] = *(const float2*)(ef + (size_t)eir[e]*DF + 2*lane);
    }
    #pragma unroll
    for (int e = 0; e < 5; ++e) {
      float2 vn;
      if (L == 0) { vn.x = vm[e].x + vf[e].x; vn.y = vm[e].y + vf[e].y; }
      else        vn = vm[e];
      float2 vt;
      vt.x = __cosf(dtr[e]*twr.x + tbr.x);
      vt.y = __cosf(dtr[e]*twr.y + tbr.y);
      float p0 = vn.x*q0[0].x + vn.y*q0[0].y + vt.x*q0[1].x + vt.y*q0[1].y
               + vef[e].x*q0[2].x + vef[e].y*q0[2].y;
      float p1 = vn.x*q1[0].x + vn.y*q1[0].y + vt.x*q1[1].x + vt.y*q1[1].y
               + vef[e].x*q1[2].x + vef[e].y*q1[2].y;
      #pragma unroll
      for (int off = 1; off < 64; off <<= 1) {
        p0 += __shfl_xor(p0, off);
        p1 += __shfl_xor(p1, off);
      }
      const bool msk = (mb >> (c0i + e)) & 1u;
      float s0 = msk ? -1e9f : p0;   // already SCALE-folded via Bqk/bias
      float s1 = msk ? -1e9f : p1;
      if (s0 > m0) {
        float f = __expf(m0 - s0);
        su0 *= f;
        c0n.x *= f; c0n.y *= f; c0t.x *= f; c0t.y *= f; c0e.x *= f; c0e.y *= f;
        m0 = s0;
      }
      float w0 = __expf(s0 - m0);
      su0 += w0;
      c0n.x += w0*vn.x;    c0n.y += w0*vn.y;
      c0t.x += w0*vt.x;    c0t.y += w0*vt.y;
      c0e.x += w0*vef[e].x; c0e.y += w0*vef[e].y;
      if (s1 > m1) {
        float f = __expf(m1 - s1);
        su1 *= f;
        c1n.x *= f; c1n.y *= f; c1t.x *= f; c1t.y *= f; c1e.x *= f; c1e.y *= f;
        m1 = s1;
      }
      float w1 = __expf(s1 - m1);
      su1 += w1;
      c1n.x += w1*vn.x;    c1n.y += w1*vn.y;
      c1t.x += w1*vt.x;    c1t.y += w1*vt.y;
      c1e.x += w1*vef[e].x; c1e.y += w1*vef[e].y;
    }
  }

  float i0 = 1.f / su0, i1 = 1.f / su1;
  c0n.x *= i0; c0n.y *= i0; c0t.x *= i0; c0t.y *= i0; c0e.x *= i0; c0e.y *= i0;
  c1n.x *= i1; c1n.y *= i1; c1t.x *= i1; c1t.y *= i1; c1e.x *= i1; c1e.y *= i1;
  unsigned* C32 = (unsigned*)(CTX + (size_t)r*768);
  C32[0*64 + lane] = packbf2(c0n);
  C32[1*64 + lane] = packbf2(c0t);
  C32[2*64 + lane] = packbf2(c0e);
  C32[3*64 + lane] = packbf2(c1n);
  C32[4*64 + lane] = packbf2(c1t);
  C32[5*64 + lane] = packbf2(c1e);
}

// ---------------- generic MFMA GEMM (acolbn: per-bn A column offset) ----------------
template<int KT, bool F32OUT, bool RELU, bool MASK>
__global__ __launch_bounds__(256, 2)
void k_gemm(const __hip_bfloat16* __restrict__ A, int lda,
            const __hip_bfloat16* __restrict__ B, int kgtot, int nblk,
            void* __restrict__ Cout, int ldc,
            const float* __restrict__ bias,
            const unsigned char* __restrict__ mask, int acolbn)
{
  __shared__ __hip_bfloat16 As[2][128*40];
  __shared__ __hip_bfloat16 Bs[2][128*32];
  const int tid  = threadIdx.x;
  const int lane = tid & 63, wid = tid >> 6;
  const int wm = wid >> 1, wn = wid & 1;
  const int rl = lane & 15, kgs = lane >> 4;
  const int bm = blockIdx.x / nblk, bn = blockIdx.x % nblk;

  f32x4 acc[4][4];
  #pragma unroll
  for (int i = 0; i < 4; ++i)
    #pragma unroll
    for (int j = 0; j < 4; ++j) acc[i][j] = (f32x4){0.f,0.f,0.f,0.f};

  #define STAGE(T, BUF) {                                                      \
    _Pragma("unroll")                                                          \
    for (int i_ = 0; i_ < 2; ++i_) {                                           \
      int row_ = i_*64 + (tid >> 2), kc_ = (tid & 3)*8;                        \
      s16x8 v_ = *(const s16x8*)(A + (size_t)(bm*128 + row_)*lda + bn*acolbn + (T)*32 + kc_); \
      *(s16x8*)(&As[BUF][row_*40 + kc_]) = v_;                                 \
    }                                                                          \
    _Pragma("unroll")                                                          \
    for (int i_ = 0; i_ < 2; ++i_) {                                           \
      int slot_ = i_*256 + tid;                                                \
      int nt_ = slot_ >> 6, kg_ = (slot_ >> 4) & 3, cl_ = slot_ & 15;          \
      s16x8 w_ = *(const s16x8*)(B + ((size_t)(bn*8 + nt_)*kgtot + (T)*4 + kg_)*128 + cl_*8); \
      *(s16x8*)(&Bs[BUF][slot_*8]) = w_;                                       \
    } }

  STAGE(0, 0);
  __syncthreads();
  int buf = 0;
  for (int t = 0; t < KT; ++t) {
    if (t < KT-1) STAGE(t+1, buf ^ 1);
    s16x8 af[4], bfm[4];
    #pragma unroll
    for (int mtl = 0; mtl < 4; ++mtl)
      af[mtl] = *(const s16x8*)(&As[buf][(wm*64 + mtl*16 + rl)*40 + kgs*8]);
    #pragma unroll
    for (int ntl = 0; ntl < 4; ++ntl)
      bfm[ntl] = *(const s16x8*)(&Bs[buf][((wn*4 + ntl)*4 + kgs)*128 + rl*8]);
    #pragma unroll
    for (int mtl = 0; mtl < 4; ++mtl)
      #pragma unroll
      for (int ntl = 0; ntl < 4; ++ntl)
        acc[mtl][ntl] = __builtin_amdgcn_mfma_f32_16x16x32_bf16(af[mtl], bfm[ntl], acc[mtl][ntl], 0, 0, 0);
    __syncthreads();
    buf ^= 1;
  }
  #undef STAGE

  #pragma unroll
  for (int mtl = 0; mtl < 4; ++mtl) {
    #pragma unroll
    for (int ntl = 0; ntl < 4; ++ntl) {
      int gcol = bn*128 + wn*64 + ntl*16 + rl;
      float bb = bias ? bias[gcol] : 0.f;
      #pragma unroll
      for (int rg = 0; rg < 4; ++rg) {
        int grow = bm*128 + wm*64 + mtl*16 + kgs*4 + rg;
        float v = acc[mtl][ntl][rg] + bb;
        if (RELU) v = fmaxf(v, 0.f);
        if (MASK) { if (mask[grow]) v = 0.f; }
        if (F32OUT) ((float*)Cout)[(size_t)grow*ldc + gcol] = v;
        else ((__hip_bfloat16*)Cout)[(size_t)grow*ldc + gcol] = __float2bfloat16(v);
      }
    }
  }
}

// ---------------- fused MLP: fc1(relu) -> LDS Hb -> fc2 ----------------
__global__ __launch_bounds__(256, 2)
void k_mlp(const __hip_bfloat16* __restrict__ A,   // FC1A, lda=384
           const __hip_bfloat16* __restrict__ B1t, // K=384,N=128 tiled
           const __hip_bfloat16* __restrict__ B2t, // K=128,N=128 tiled
           const float* __restrict__ b1, const float* __restrict__ b2,
           float* __restrict__ Cout)               // ldc=128
{
  __shared__ __hip_bfloat16 As[2][128*40];
  __shared__ __hip_bfloat16 Bs[2][128*32];
  __shared__ __hip_bfloat16 Hb[128*136];
  const int tid  = threadIdx.x;
  const int lane = tid & 63, wid = tid >> 6;
  const int wm = wid >> 1, wn = wid & 1;
  const int rl = lane & 15, kgs = lane >> 4;
  const int bm = blockIdx.x;

  f32x4 acc[4][4];
  #pragma unroll
  for (int i = 0; i < 4; ++i)
    #pragma unroll
    for (int j = 0; j < 4; ++j) acc[i][j] = (f32x4){0.f,0.f,0.f,0.f};

  // ---- phase 1: fc1, KT=12, kgtot=48, single n-block ----
  #define STAGE1(T, BUF) {                                                     \
    _Pragma("unroll")                                                          \
    for (int i_ = 0; i_ < 2; ++i_) {                                           \
      int row_ = i_*64 + (tid >> 2), kc_ = (tid & 3)*8;                        \
      s16x8 v_ = *(const s16x8*)(A + (size_t)(bm*128 + row_)*384 + (T)*32 + kc_); \
      *(s16x8*)(&As[BUF][row_*40 + kc_]) = v_;                                 \
    }                                                                          \
    _Pragma("unroll")                                                          \
    for (int i_ = 0; i_ < 2; ++i_) {                                           \
      int slot_ = i_*256 + tid;                                                \
      int nt_ = slot_ >> 6, kg_ = (slot_ >> 4) & 3, cl_ = slot_ & 15;          \
      s16x8 w_ = *(const s16x8*)(B1t + ((size_t)nt_*48 + (T)*4 + kg_)*128 + cl_*8); \
      *(s16x8*)(&Bs[BUF][slot_*8]) = w_;                                       \
    } }

  STAGE1(0, 0);
  __syncthreads();
  int buf = 0;
  for (int t = 0; t < 12; ++t) {
    if (t < 11) STAGE1(t+1, buf ^ 1);
    s16x8 af[4], bfm[4];
    #pragma unroll
    for (int mtl = 0; mtl < 4; ++mtl)
      af[mtl] = *(const s16x8*)(&As[buf][(wm*64 + mtl*16 + rl)*40 + kgs*8]);
    #pragma unroll
    for (int ntl = 0; ntl < 4; ++ntl)
      bfm[ntl] = *(const s16x8*)(&Bs[buf][((wn*4 + ntl)*4 + kgs)*128 + rl*8]);
    #pragma unroll
    for (int mtl = 0; mtl < 4; ++mtl)
      #pragma unroll
      for (int ntl = 0; ntl < 4; ++ntl)
        acc[mtl][ntl] = __builtin_amdgcn_mfma_f32_16x16x32_bf16(af[mtl], bfm[ntl], acc[mtl][ntl], 0, 0, 0);
    __syncthreads();
    buf ^= 1;
  }
  #undef STAGE1

  // relu + bias -> Hb (bf16, pad 136)
  #pragma unroll
  for (int mtl = 0; mtl < 4; ++mtl) {
    #pragma unroll
    for (int ntl = 0; ntl < 4; ++ntl) {
      int col = wn*64 + ntl*16 + rl;
      float bb = b1[col];
      #pragma unroll
      for (int rg = 0; rg < 4; ++rg) {
        int row = wm*64 + mtl*16 + kgs*4 + rg;
        union { __hip_bfloat16 h; short s; } u;
        u.s = f2bf(fmaxf(acc[mtl][ntl][rg] + bb, 0.f));
        Hb[row*136 + col] = u.h;
      }
    }
  }

  // ---- phase 2: fc2 from Hb (LDS), KT=4, kgtot=16 ----
  f32x4 acc2[4][4];
  #pragma unroll
  for (int i = 0; i < 4; ++i)
    #pragma unroll
    for (int j = 0; j < 4; ++j) acc2[i][j] = (f32x4){0.f,0.f,0.f,0.f};

  #define STAGE2(T, BUF) {                                                     \
    _Pragma("unroll")                                                          \
    for (int i_ = 0; i_ < 2; ++i_) {                                           \
      int slot_ = i_*256 + tid;                                                \
      int nt_ = slot_ >> 6, kg_ = (slot_ >> 4) & 3, cl_ = slot_ & 15;          \
      s16x8 w_ = *(const s16x8*)(B2t + ((size_t)nt_*16 + (T)*4 + kg_)*128 + cl_*8); \
      *(s16x8*)(&Bs[BUF][slot_*8]) = w_;                                       \
    } }

  STAGE2(0, 0);
  __syncthreads();        // also publishes Hb
  buf = 0;
  for (int t = 0; t < 4; ++t) {
    if (t < 3) STAGE2(t+1, buf ^ 1);
    s16x8 af[4], bfm[4];
    #pragma unroll
    for (int mtl = 0; mtl < 4; ++mtl)
      af[mtl] = *(const s16x8*)(&Hb[(wm*64 + mtl*16 + rl)*136 + t*32 + kgs*8]);
    #pragma unroll
    for (int ntl = 0; ntl < 4; ++ntl)
      bfm[ntl] = *(const s16x8*)(&Bs[buf][((wn*4 + ntl)*4 + kgs)*128 + rl*8]);
    #pragma unroll
    for (int mtl = 0; mtl < 4; ++mtl)
      #pragma unroll
      for (int ntl = 0; ntl < 4; ++ntl)
        acc2[mtl][ntl] = __builtin_amdgcn_mfma_f32_16x16x32_bf16(af[mtl], bfm[ntl], acc2[mtl][ntl], 0, 0, 0);
    __syncthreads();
    buf ^= 1;
  }
  #undef STAGE2

  #pragma unroll
  for (int mtl = 0; mtl < 4; ++mtl) {
    #pragma unroll
    for (int ntl = 0; ntl < 4; ++ntl) {
      int gcol = wn*64 + ntl*16 + rl;
      float bb = b2[gcol];
      #pragma unroll
      for (int rg = 0; rg < 4; ++rg) {
        int grow = bm*128 + wm*64 + mtl*16 + kgs*4 + rg;
        Cout[(size_t)grow*128 + gcol] = acc2[mtl][ntl][rg] + bb;
      }
    }
  }
}

// ---------------- host ----------------
extern "C" void kernel_launch(void* const* d_in, const int* in_sizes, int n_in,
                              void* d_out, int out_size, void* d_ws, size_t ws_size,
                              hipStream_t stream) {
  (void)in_sizes; (void)n_in; (void)out_size; (void)ws_size; (void)d_ws;
  const float* nf   = (const float*)d_in[0];
  const float* ef   = (const float*)d_in[1];
  const float* mem  = (const float*)d_in[2];
  const float* tsv  = (const float*)d_in[3];
  const float* ets  = (const float*)d_in[4];
  const float* etn  = (const float*)d_in[5];
  const float* tw   = (const float*)d_in[6];
  const float* tb   = (const float*)d_in[7];
  const float* Wq   = (const float*)d_in[8];
  const float* bq   = (const float*)d_in[9];
  const float* Wk   = (const float*)d_in[10];
  const float* bv   = (const float*)d_in[13];
  const float* Wv   = (const float*)d_in[12];
  const float* Wo   = (const float*)d_in[14];
  const float* bo   = (const float*)d_in[15];
  const float* f1w  = (const float*)d_in[16];
  const float* f1b  = (const float*)d_in[17];
  const float* f2w  = (const float*)d_in[18];
  const float* f2b  = (const float*)d_in[19];
  const int* srcn   = (const int*)d_in[20];
  const int* nbs    = (const int*)d_in[21];
  const int* eis    = (const int*)d_in[22];
  const int* nbn    = (const int*)d_in[23];
  const int* ein    = (const int*)d_in[24];
  float* out = (float*)d_out;

  __hip_bfloat16 *S, *QKH, *CTX, *Ob, *FC1A, *Bqk, *Bv, *Bo, *B1, *B2;
  float *bqkv, *out1f;
  unsigned char* allm;
  hipGetSymbolAddress((void**)&S,    HIP_SYMBOL(g_S));
  hipGetSymbolAddress((void**)&QKH,  HIP_SYMBOL(g_QKH));
  hipGetSymbolAddress((void**)&CTX,  HIP_SYMBOL(g_CTX));
  hipGetSymbolAddress((void**)&Ob,   HIP_SYMBOL(g_Ob));
  hipGetSymbolAddress((void**)&FC1A, HIP_SYMBOL(g_FC1A));
  hipGetSymbolAddress((void**)&Bqk,  HIP_SYMBOL(g_Bqk));
  hipGetSymbolAddress((void**)&Bv,   HIP_SYMBOL(g_Bv));
  hipGetSymbolAddress((void**)&Bo,   HIP_SYMBOL(g_Bo));
  hipGetSymbolAddress((void**)&B1,   HIP_SYMBOL(g_B1));
  hipGetSymbolAddress((void**)&B2,   HIP_SYMBOL(g_B2));
  hipGetSymbolAddress((void**)&bqkv, HIP_SYMBOL(g_bqkv));
  hipGetSymbolAddress((void**)&out1f,HIP_SYMBOL(g_out1));
  hipGetSymbolAddress((void**)&allm, HIP_SYMBOL(g_allm));

  hipLaunchKernelGGL(k_wprep1, dim3(1760), dim3(256), 0, stream, Wq, Wk, bq, Wv, Wo, f1w, f2w);
  hipLaunchKernelGGL(k_wprep2, dim3(102), dim3(256), 0, stream, tb);

  // ---- layer 0 (R = 43008) ----
  {
    const int R = NR1, BMg = R/128;
    hipLaunchKernelGGL((k_prep<0>), dim3(R/8), dim3(256), 0, stream, nf, mem, srcn, nbs);
    hipLaunchKernelGGL((k_gemm<4,false,false,false>), dim3(BMg*6), dim3(256), 0, stream,
        S, 128, Bqk, 16, 6, QKH, 768, bqkv, (const unsigned char*)nullptr, 0);
    hipLaunchKernelGGL((k_edge<0>), dim3(R/4), dim3(256), 0, stream,
        nf, ef, mem, tsv, ets, etn, tw, tb, nbs, eis, nbn, ein, QKH, CTX);
    hipLaunchKernelGGL((k_gemm<12,false,false,false>), dim3(BMg*2), dim3(256), 0, stream,
        CTX, 768, Bv, 48, 2, Ob, 256, bv, (const unsigned char*)nullptr, 384);
    hipLaunchKernelGGL((k_gemm<8,false,false,true>), dim3(BMg*2), dim3(256), 0, stream,
        Ob, 256, Bo, 32, 2, FC1A, 384, bo, allm, 0);
    hipLaunchKernelGGL(k_mlp, dim3(BMg), dim3(256), 0, stream,
        FC1A, B1, B2, f1b, f2b, out1f);
  }
  // ---- layer 1 (R = 2048) ----
  {
    const int R = NB, BMg = R/128;
    hipLaunchKernelGGL((k_prep<1>), dim3(R/8), dim3(256), 0, stream, nf, mem, srcn, nbs);
    hipLaunchKernelGGL((k_gemm<4,false,false,false>), dim3(BMg*6), dim3(256), 0, stream,
        S, 128, Bqk + 98304, 16, 6, QKH, 768, bqkv + 768, (const unsigned char*)nullptr, 0);
    hipLaunchKernelGGL((k_edge<1>), dim3(R/4), dim3(256), 0, stream,
        nf, ef, mem, tsv, ets, etn, tw, tb, nbs, eis, nbn, ein, QKH, CTX);
    hipLaunchKernelGGL((k_gemm<12,false,false,false>), dim3(BMg*2), dim3(256), 0, stream,
        CTX, 768, Bv + 2*49152, 48, 2, Ob, 256, bv + 256, (const unsigned char*)nullptr, 384);
    hipLaunchKernelGGL((k_gemm<8,false,false,true>), dim3(BMg*2), dim3(256), 0, stream,
        Ob, 256, Bo + 65536, 32, 2, FC1A, 384, bo + 256, allm, 0);
    hipLaunchKernelGGL(k_mlp, dim3(BMg), dim3(256), 0, stream,
        FC1A, B1 + 49152, B2 + 16384, f1b + 128, f2b + 128, out);
  }
}